// Round 2
// 462.648 us; speedup vs baseline: 1.3218x; 1.3218x over previous
//
#include <hip/hip_runtime.h>
#include <hip/hip_bf16.h>

typedef __attribute__((ext_vector_type(8))) short s8v;
typedef __attribute__((ext_vector_type(4))) short s4v;
typedef __attribute__((ext_vector_type(4))) float f4v;

#define MFMA32(A,B,C) __builtin_amdgcn_mfma_f32_16x16x32_bf16(A,B,C,0,0,0)
#define MFMA16(A,B,C) __builtin_amdgcn_mfma_f32_16x16x16bf16_1k(A,B,C,0,0,0)

__device__ __forceinline__ unsigned short f2bf(float f){
  unsigned int u = __float_as_uint(f);
  u += 0x7FFFu + ((u>>16)&1u);
  return (unsigned short)(u>>16);
}
__device__ __forceinline__ float bf2f(unsigned short s){
  return __uint_as_float(((unsigned int)s)<<16);
}
// packed f32x4 -> bf16x4 via v_cvt_pk_bf16_f32 (RNE, same rounding as f2bf)
__device__ __forceinline__ s4v pack4(f4v v){
  float2 lo; lo.x=v[0]; lo.y=v[1];
  float2 hi; hi.x=v[2]; hi.y=v[3];
  __hip_bfloat162 a = __float22bfloat162_rn(lo);
  __hip_bfloat162 b = __float22bfloat162_rn(hi);
  union{ s4v s; unsigned int u[2]; } r;
  __builtin_memcpy(&r.u[0], &a, 4);
  __builtin_memcpy(&r.u[1], &b, 4);
  return r.s;
}

// log2(e)/8  (fold the 1/sqrt(dh)=1/8 score scale into exp2)
#define EXPC 0.18033688011112042f

// lgkm-only barrier: LDS ordering without draining vmcnt (keeps global
// prefetch loads in flight across the sync). Sandwiched in memory-clobber
// asm so the compiler cannot move LDS ops across it (s_barrier intrinsic
// itself is IntrNoMem).
#define BARRIER() do{                                        \
  asm volatile("s_waitcnt lgkmcnt(0)" ::: "memory");         \
  __builtin_amdgcn_s_barrier();                              \
  asm volatile("" ::: "memory");                             \
}while(0)

// ---------------------------------------------------------------------------
// K0: Wo' [o][h*64+j] = Wo[o][j*16+h], bf16   (launched AFTER fused_attn;
// wop overlaps the then-dead qh region)
// ---------------------------------------------------------------------------
__global__ void pack_wo(const float* __restrict__ wo, unsigned short* __restrict__ wop){
  int idx = blockIdx.x*256 + threadIdx.x;
  if(idx >= 1024*1024) return;
  int o = idx >> 10, r = idx & 1023, h = r >> 6, j = r & 63;
  wop[idx] = f2bf(wo[o*1024 + j*16 + h]);
}

// ---------------------------------------------------------------------------
// K1: projections. C[m,n] = sum_k A[m,k] * W[n,k] + bias[n]
//   z=0: KEY  -> kh[b][h][s][j]     (j = n>>4, h = n&15)
//   z=1: QUERY-> qh[b][h][s][j]
//   z=2: VALUE-> vt[b][h][j][s]     (transposed for PV A-fragments)
// ---------------------------------------------------------------------------
__global__ __launch_bounds__(256) void proj_gemm(
    const float* __restrict__ KEY, const float* __restrict__ VALUE, const float* __restrict__ QUERY,
    const float* __restrict__ Wk, const float* __restrict__ bk,
    const float* __restrict__ Wq, const float* __restrict__ bq,
    const float* __restrict__ Wv, const float* __restrict__ bv,
    unsigned short* __restrict__ kh, unsigned short* __restrict__ qh,
    unsigned short* __restrict__ vt)
{
  __shared__ short As[128*64];
  __shared__ short Bs[128*64];
  const int t = threadIdx.x;
  const int z = blockIdx.z;
  const float* A; const float* W; const float* bias;
  if(z==0){A=KEY;   W=Wk; bias=bk;}
  else if(z==1){A=QUERY; W=Wq; bias=bq;}
  else {A=VALUE; W=Wv; bias=bv;}
  const int m0 = blockIdx.x*128, n0 = blockIdx.y*128;
  const int l = t&63, w = t>>6;
  const int wm = (w>>1)*64, wn = (w&1)*64;
  const int row16 = l&15, quad = l>>4;
  f4v acc[4][4];
  #pragma unroll
  for(int i=0;i<4;i++)
    #pragma unroll
    for(int j=0;j<4;j++) acc[i][j] = (f4v){0.f,0.f,0.f,0.f};

  const int sr = t>>4, sc = t&15;
  for(int k0=0;k0<1024;k0+=64){
    #pragma unroll
    for(int p=0;p<8;p++){
      float4 av = *(const float4*)&A[(size_t)(m0 + p*16 + sr)*1024 + k0 + sc*4];
      float4 bvv= *(const float4*)&W[(size_t)(n0 + p*16 + sr)*1024 + k0 + sc*4];
      *(s4v*)&As[(p*16+sr)*64 + sc*4] = pack4((f4v){av.x,av.y,av.z,av.w});
      *(s4v*)&Bs[(p*16+sr)*64 + sc*4] = pack4((f4v){bvv.x,bvv.y,bvv.z,bvv.w});
    }
    __syncthreads();
    #pragma unroll
    for(int kk=0; kk<64; kk+=32){
      s8v af[4], bf[4];
      #pragma unroll
      for(int mt=0;mt<4;mt++) af[mt] = *(const s8v*)&As[(wm+mt*16+row16)*64 + kk + quad*8];
      #pragma unroll
      for(int nt=0;nt<4;nt++) bf[nt] = *(const s8v*)&Bs[(wn+nt*16+row16)*64 + kk + quad*8];
      #pragma unroll
      for(int mt=0;mt<4;mt++)
        #pragma unroll
        for(int nt=0;nt<4;nt++)
          acc[mt][nt] = MFMA32(af[mt], bf[nt], acc[mt][nt]);
    }
    __syncthreads();
  }

  #pragma unroll
  for(int nt=0;nt<4;nt++){
    const int n = n0 + wn + nt*16 + row16;
    const float bias_n = bias[n];
    const int hh = n & 15, jj = n >> 4;
    #pragma unroll
    for(int mt=0;mt<4;mt++){
      #pragma unroll
      for(int r=0;r<4;r++){
        const int m = m0 + wm + mt*16 + quad*4 + r;
        const float val = acc[mt][nt][r] + bias_n;
        const int bb = m>>11, ss = m&2047;
        if(z==2)
          vt[(size_t)((bb*16+hh)*64 + jj)*2048 + ss] = f2bf(val);
        else if(z==0)
          kh[(size_t)((bb*16+hh)*2048 + ss)*64 + jj] = f2bf(val);
        else
          qh[(size_t)((bb*16+hh)*2048 + ss)*64 + jj] = f2bf(val);
      }
    }
  }
}

// ---------------------------------------------------------------------------
// K2: fused attention, v2.
//   - grid: 1-D 512 blocks; combo = bid&7 -> (ih = combo&3, b = combo>>2).
//     Round-robin dispatch pins each (b,ih) combo to one XCD; its K+V slice
//     (2 MB + 2 MB, i-range 512) fits that XCD's 4 MB L2.
//   - K and V i32-tiles staged in LDS once per block, shared by both
//     q-groups (halves L2-side traffic).
//   - K tile XOR-swizzled (16B slot ^= row&7) -> conflict-free ds_read_b128
//     fragment reads.  V rows are 64B -> ~2-way (free), kept linear.
//   - Two lgkm-only barriers per iter (epoch A / epoch B).  Global prefetch
//     (K of tile t+1, reg-staged, ds-written in epoch B) stays in flight
//     across barriers: no vmcnt(0) drain anywhere in the loop.
//   - Softmax over heads: per-wave 4-head partial denominators exchanged in
//     LDS (single buffer; write epoch A / read epoch B / next write after
//     bar-end => race-free).
//   - P pack + output pack via v_cvt_pk_bf16_f32.
// ---------------------------------------------------------------------------
__global__ __launch_bounds__(512,2) void fused_attn(
    const unsigned short* __restrict__ kh, const unsigned short* __restrict__ qh,
    const unsigned short* __restrict__ vt, unsigned short* __restrict__ opart)
{
  __shared__ unsigned short Ks[512*64];    // [h*32+i][j], swizzled, 64 KB
  __shared__ unsigned short Vs[1024*32];   // [h*64+j][i], linear,  64 KB
  __shared__ f4v dpart[2][4][2][64];       // [qg][hg][sub][lane],  16 KB

  const int t=threadIdx.x, l=t&63, w=t>>6;
  const int qg=w>>2, hg=w&3;
  const int row16=l&15, quad=l>>4;
  const int bid=blockIdx.x;
  const int combo=bid&7, qb=bid>>3;
  const int ih=combo&3, b=combo>>2;
  const int q0=qb*32+qg*16, h0=hg*4;
  const int ibase=ih*512;

  // Q fragments (global, once)
  s8v qf[4][2];
  #pragma unroll
  for(int hh=0;hh<4;hh++){
    const unsigned short* qp=&qh[(size_t)((b*16+h0+hh)*2048 + q0+row16)*64];
    qf[hh][0]=*(const s8v*)&qp[quad*8];
    qf[hh][1]=*(const s8v*)&qp[32+quad*8];
  }

  // staging roles: K = 512 rows x 128B (8 passes x 64 rows, 8 slots x 16B)
  //                V = 1024 rows x 64B (8 passes x 128 rows, 4 slots x 16B)
  const int rkb=t>>3, ksl=t&7;
  const int rvb=t>>2, vsl=t&3;

  f4v o[4][4];
  #pragma unroll
  for(int i=0;i<4;i++)
    #pragma unroll
    for(int j=0;j<4;j++) o[i][j]=(f4v){0.f,0.f,0.f,0.f};

  s8v kreg[8];
  // prologue: stage K(0)
  #pragma unroll
  for(int p=0;p<8;p++){
    int rr=p*64+rkb, h=rr>>5, i=rr&31;
    kreg[p]=*(const s8v*)&kh[((size_t)(b*16+h)*2048 + ibase + i)*64 + ksl*8];
  }
  #pragma unroll
  for(int p=0;p<8;p++){
    int rr=p*64+rkb;
    *(s8v*)&Ks[rr*64 + ((ksl^(rr&7))<<3)] = kreg[p];
  }
  BARRIER();

  #pragma unroll 1
  for(int it=0; it<16; ++it){
    const int i0=it*32;
    const int i0n=(i0+32)&511;        // wrap: last prefetch is harmless
    // ---------------- epoch A: Ks holds K(t); fill Vs = V(t) ----------------
    s8v vtmp[8];
    #pragma unroll
    for(int p=0;p<8;p++){             // V(t): in flight across QK compute
      int rv=p*128+rvb, h=rv>>6, j=rv&63;
      vtmp[p]=*(const s8v*)&vt[((size_t)(b*16+h)*64 + j)*2048 + ibase + i0 + vsl*8];
    }
    #pragma unroll
    for(int p=0;p<8;p++){             // K(t+1): in flight until epoch B write
      int rr=p*64+rkb, h=rr>>5, i=rr&31;
      kreg[p]=*(const s8v*)&kh[((size_t)(b*16+h)*2048 + ibase + i0n + i)*64 + ksl*8];
    }
    f4v e0[4], e1[4];
    const int sw0=(quad^(row16&7))<<3, sw1=((4+quad)^(row16&7))<<3;
    #pragma unroll
    for(int hh=0;hh<4;hh++){
      const unsigned short* k0p=&Ks[((h0+hh)*32+row16)*64];
      const unsigned short* k1p=&Ks[((h0+hh)*32+16+row16)*64];
      f4v S0={0.f,0.f,0.f,0.f}, S1={0.f,0.f,0.f,0.f};
      S0=MFMA32(*(const s8v*)&k0p[sw0], qf[hh][0], S0);
      S0=MFMA32(*(const s8v*)&k0p[sw1], qf[hh][1], S0);
      S1=MFMA32(*(const s8v*)&k1p[sw0], qf[hh][0], S1);
      S1=MFMA32(*(const s8v*)&k1p[sw1], qf[hh][1], S1);
      #pragma unroll
      for(int r=0;r<4;r++){
        e0[hh][r]=__builtin_amdgcn_exp2f(S0[r]*EXPC);
        e1[hh][r]=__builtin_amdgcn_exp2f(S1[r]*EXPC);
      }
    }
    f4v d0=(e0[0]+e0[1])+(e0[2]+e0[3]);
    f4v d1=(e1[0]+e1[1])+(e1[2]+e1[3]);
    #pragma unroll
    for(int p=0;p<8;p++){
      int rv=p*128+rvb;
      *(s8v*)&Vs[rv*32 + vsl*8] = vtmp[p];
    }
    dpart[qg][hg][0][l]=d0;
    dpart[qg][hg][1][l]=d1;
    BARRIER();   // bar-mid: dpart + Vs visible; vmem (kreg) stays in flight
    // ---------------- epoch B: reduce denom, write K(t+1), PV --------------
    f4v s0=(dpart[qg][0][0][l]+dpart[qg][1][0][l])+(dpart[qg][2][0][l]+dpart[qg][3][0][l]);
    f4v s1=(dpart[qg][0][1][l]+dpart[qg][1][1][l])+(dpart[qg][2][1][l]+dpart[qg][3][1][l]);
    f4v r0,r1;
    #pragma unroll
    for(int r=0;r<4;r++){
      r0[r]=__builtin_amdgcn_rcpf(s0[r]);
      r1[r]=__builtin_amdgcn_rcpf(s1[r]);
    }
    #pragma unroll
    for(int p=0;p<8;p++){             // K(t+1) -> Ks (readers of K(t) are past bar-mid)
      int rr=p*64+rkb;
      *(s8v*)&Ks[rr*64 + ((ksl^(rr&7))<<3)] = kreg[p];
    }
    s4v p0[4],p1[4];
    #pragma unroll
    for(int hh=0;hh<4;hh++){
      p0[hh]=pack4(e0[hh]*r0);
      p1[hh]=pack4(e1[hh]*r1);
    }
    #pragma unroll
    for(int hh=0;hh<4;hh++){
      #pragma unroll
      for(int jt=0;jt<4;jt++){
        const unsigned short* vp=&Vs[((h0+hh)*64 + jt*16 + row16)*32];
        s4v v0=*(const s4v*)&vp[quad*4];
        s4v v1=*(const s4v*)&vp[16+quad*4];
        o[hh][jt]=MFMA16(v0,p0[hh],o[hh][jt]);
        o[hh][jt]=MFMA16(v1,p1[hh],o[hh][jt]);
      }
    }
    BARRIER();   // bar-end: Ks(t+1) visible; Vs/dpart reads drained
  }

  // store bf16 partial: opart[ih][b][q][h*64+j]
  #pragma unroll
  for(int hh=0;hh<4;hh++)
    #pragma unroll
    for(int jt=0;jt<4;jt++)
      *(s4v*)&opart[(size_t)((ih*2+b)*2048 + q0+row16)*1024 + (h0+hh)*64 + jt*16 + quad*4]
        = pack4(o[hh][jt]);
}

// ---------------------------------------------------------------------------
// K3: reduce the 4 i-quarter partials -> out2 bf16
// ---------------------------------------------------------------------------
__global__ __launch_bounds__(256) void reduce_o(
    const unsigned short* __restrict__ op, unsigned short* __restrict__ out2)
{
  size_t e = ((size_t)blockIdx.x*256 + threadIdx.x)*8;
  s8v a = *(const s8v*)&op[e];
  s8v b = *(const s8v*)&op[(size_t)4194304 + e];
  s8v c = *(const s8v*)&op[(size_t)2*4194304 + e];
  s8v d = *(const s8v*)&op[(size_t)3*4194304 + e];
  f4v lo, hi;
  #pragma unroll
  for(int i=0;i<4;i++)
    lo[i] = (bf2f((unsigned short)a[i])+bf2f((unsigned short)b[i]))
          + (bf2f((unsigned short)c[i])+bf2f((unsigned short)d[i]));
  #pragma unroll
  for(int i=0;i<4;i++)
    hi[i] = (bf2f((unsigned short)a[i+4])+bf2f((unsigned short)b[i+4]))
          + (bf2f((unsigned short)c[i+4])+bf2f((unsigned short)d[i+4]));
  *(s4v*)&out2[e]   = pack4(lo);
  *(s4v*)&out2[e+4] = pack4(hi);
}

// ---------------------------------------------------------------------------
// K4: res[m][n] = sum_k out2[m,k]*WoP[n,k] + bo[n], fp32 out
// ---------------------------------------------------------------------------
__global__ __launch_bounds__(256) void out_gemm(
    const unsigned short* __restrict__ A, const unsigned short* __restrict__ Bm,
    const float* __restrict__ bias, float* __restrict__ out)
{
  __shared__ short As[128*64];
  __shared__ short Bs[128*64];
  const int t=threadIdx.x, l=t&63, w=t>>6;
  const int row16=l&15, quad=l>>4;
  const int m0=blockIdx.x*128, n0=blockIdx.y*128;
  const int wm=(w>>1)*64, wn=(w&1)*64;
  f4v acc[4][4];
  #pragma unroll
  for(int i=0;i<4;i++)
    #pragma unroll
    for(int j=0;j<4;j++) acc[i][j] = (f4v){0.f,0.f,0.f,0.f};

  const int sr=t>>3, sc=(t&7)*8;
  for(int k0=0;k0<1024;k0+=64){
    #pragma unroll
    for(int p=0;p<4;p++){
      *(s8v*)&As[(p*32+sr)*64 + sc] = *(const s8v*)&A [(size_t)(m0+p*32+sr)*1024 + k0 + sc];
      *(s8v*)&Bs[(p*32+sr)*64 + sc] = *(const s8v*)&Bm[(size_t)(n0+p*32+sr)*1024 + k0 + sc];
    }
    __syncthreads();
    #pragma unroll
    for(int kk=0; kk<64; kk+=32){
      s8v af[4], bf[4];
      #pragma unroll
      for(int mt=0;mt<4;mt++) af[mt] = *(const s8v*)&As[(wm+mt*16+row16)*64 + kk + quad*8];
      #pragma unroll
      for(int nt=0;nt<4;nt++) bf[nt] = *(const s8v*)&Bs[(wn+nt*16+row16)*64 + kk + quad*8];
      #pragma unroll
      for(int mt=0;mt<4;mt++)
        #pragma unroll
        for(int nt=0;nt<4;nt++)
          acc[mt][nt] = MFMA32(af[mt], bf[nt], acc[mt][nt]);
    }
    __syncthreads();
  }
  #pragma unroll
  for(int nt=0;nt<4;nt++){
    const int n = n0+wn+nt*16+row16;
    const float bias_n = bias[n];
    #pragma unroll
    for(int mt=0;mt<4;mt++)
      #pragma unroll
      for(int r=0;r<4;r++){
        const int m = m0+wm+mt*16+quad*4+r;
        out[(size_t)m*1024 + n] = acc[mt][nt][r] + bias_n;
      }
  }
}

// ---------------------------------------------------------------------------
// Workspace (56 MiB):
//   kh    @ 0        (8 MiB)  [2][16][2048][64]   dead after fused_attn
//   qh    @ 8 MiB    (8 MiB)                      dead after fused_attn
//   vt    @ 16 MiB   (8 MiB)  [2][16][64][2048]   dead after fused_attn
//   opart @ 24 MiB   (32 MiB) [4ih][2b][2048][1024]
//   out2  @ 0        (8 MiB)  overlaps dead kh
//   wop   @ 8 MiB    (2 MiB)  overlaps dead qh (pack_wo runs after fused_attn)
// ---------------------------------------------------------------------------
extern "C" void kernel_launch(void* const* d_in, const int* in_sizes, int n_in,
                              void* d_out, int out_size, void* d_ws, size_t ws_size,
                              hipStream_t stream)
{
  const float* KEY   = (const float*)d_in[0];
  const float* VALUE = (const float*)d_in[1];
  const float* QUERY = (const float*)d_in[2];
  const float* Wk = (const float*)d_in[3];
  const float* bk = (const float*)d_in[4];
  const float* Wq = (const float*)d_in[5];
  const float* bq = (const float*)d_in[6];
  const float* Wv = (const float*)d_in[7];
  const float* bv = (const float*)d_in[8];
  const float* Wo = (const float*)d_in[9];
  const float* bo = (const float*)d_in[10];

  char* ws = (char*)d_ws;
  unsigned short* kh   = (unsigned short*)(ws);
  unsigned short* qh   = (unsigned short*)(ws +  8388608);
  unsigned short* vt   = (unsigned short*)(ws + 16777216);
  unsigned short* opart= (unsigned short*)(ws + 25165824);
  unsigned short* out2 = (unsigned short*)(ws);             // overlap kh
  unsigned short* wop  = (unsigned short*)(ws +  8388608);  // overlap qh

  proj_gemm <<<dim3(32,8,3), dim3(256), 0, stream>>>(KEY,VALUE,QUERY,Wk,bk,Wq,bq,Wv,bv,kh,qh,vt);
  fused_attn<<<dim3(512),    dim3(512), 0, stream>>>(kh,qh,vt,opart);
  pack_wo   <<<dim3(4096),   dim3(256), 0, stream>>>(Wo,wop);
  reduce_o  <<<dim3(2048),   dim3(256), 0, stream>>>(opart,out2);
  out_gemm  <<<dim3(32,8),   dim3(256), 0, stream>>>(out2,wop,bo,(float*)d_out);
}